// Round 10
// baseline (484.192 us; speedup 1.0000x reference)
//
#include <hip/hip_runtime.h>
#include <hip/hip_bf16.h>

// Problem constants (B=2, S=2048, D=2048, H=16, dk=128)
#define SEQ   2048
#define DIM   2048
#define NH    16
#define DKH   128
#define BATCH 2
#define MROWS (BATCH * SEQ)   // 4096
#define NQT   (SEQ / 64)      // 32 q-tiles per (b,h)

using bf16 = __hip_bfloat16;
typedef __attribute__((ext_vector_type(8))) short short8;
typedef __attribute__((ext_vector_type(4))) float floatx4;
typedef __attribute__((ext_vector_type(4))) int intx4;   // nontemporal-safe 16B

union BfBits { bf16 h; short s; };

// async global->LDS, 16 bytes per lane (wave-uniform LDS base + lane*16;
// global source address is per-lane)
__device__ __forceinline__ void gl_lds16(const bf16* g, bf16* l) {
  __builtin_amdgcn_global_load_lds(
      (__attribute__((address_space(1))) void*)(g),
      (__attribute__((address_space(3))) void*)(l), 16, 0, 0);
}

#define S_BAR  __builtin_amdgcn_s_barrier()
#define VMCNT6 do { asm volatile("s_waitcnt vmcnt(6)" ::: "memory"); __builtin_amdgcn_sched_barrier(0); } while (0)
#define VMCNT0 do { asm volatile("s_waitcnt vmcnt(0)" ::: "memory"); __builtin_amdgcn_sched_barrier(0); } while (0)
#define LGKM0  do { asm volatile("s_waitcnt lgkmcnt(0)" ::: "memory"); __builtin_amdgcn_sched_barrier(0); } while (0)

// ---------------- merged cast fp32 -> bf16 for x + 4 weights ----------------
__global__ __launch_bounds__(256) void cast5_kernel(const float* __restrict__ x,
                                                    const float* __restrict__ wq,
                                                    const float* __restrict__ wk,
                                                    const float* __restrict__ wv,
                                                    const float* __restrict__ wo,
                                                    bf16* __restrict__ dst,
                                                    int nX4, int nW4, int nTot) {
  int i = blockIdx.x * 256 + threadIdx.x;
  if (i >= nTot) return;
  const float* src;
  int off;
  int j = i - nX4;
  if (j < 0) { src = x; off = i; }
  else {
    int wsel = j >> 20;          // nW4 = 2^20
    off = j & (nW4 - 1);
    src = (wsel == 0) ? wq : (wsel == 1) ? wk : (wsel == 2) ? wv : wo;
  }
  float4 v = reinterpret_cast<const float4*>(src)[off];
  __hip_bfloat162 h01, h23;
  h01.x = __float2bfloat16(v.x); h01.y = __float2bfloat16(v.y);
  h23.x = __float2bfloat16(v.z); h23.y = __float2bfloat16(v.w);
  reinterpret_cast<__hip_bfloat162*>(dst)[i * 2 + 0] = h01;
  reinterpret_cast<__hip_bfloat162*>(dst)[i * 2 + 1] = h23;
}

// ============ pipelined 256x128 GEMM, BK=64, 3-buffer, phase-interleaved =====
// K-loop identical to R5 (114.8 us, MfmaUtil 39.4%, conflicts 0).
// R9 epilogue (MODE 0): RoPE (Q,K) + V transpose fused as in R8, but with
// vectorized coalesced stores (LDS round-trip for Q/K) and nontemporal stores
// everywhere (R8 post-mortem: scalar 2B stores caused RFO fetches and the
// write stream evicted the K-loop's A/B panels -> +58 MB FETCH, +47 us).
#define BUFE (256 * 64 + 128 * 64)   // 24576 elems per buffer

template <int ROWS>
__device__ __forceinline__ void stage_swz(const bf16* __restrict__ G, bf16* lds,
                                          int row0, int k0, int w, int l) {
  const int rr = w * 8 + (l >> 3);                 // row within 64-row issue
  const int cc = ((l & 7) * 8) ^ ((l >> 3) * 8);   // pre-swizzled col (elems)
#pragma unroll
  for (int u = 0; u < ROWS / 64; ++u)
    gl_lds16(G + (size_t)(row0 + u * 64 + rr) * DIM + k0 + cc,
             lds + (u * 64 + w * 8) * 64);
}

template <int MODE>
__global__ __launch_bounds__(512, 2) void gemm256(const bf16* __restrict__ A,
                                                  const bf16* __restrict__ Bw,
                                                  bf16* __restrict__ Qb,
                                                  bf16* __restrict__ Kb,
                                                  float* __restrict__ Kout,
                                                  float* __restrict__ Vout,
                                                  bf16* __restrict__ Vt,
                                                  const float* __restrict__ cosT,
                                                  const float* __restrict__ sinT,
                                                  float* __restrict__ Cout) {
  __shared__ bf16 smem[3 * BUFE];  // [buf] { A 256x64 | B 128x64 }

  const int t = threadIdx.x;
  const int w = t >> 6, l = t & 63;
  const int lr = l & 15, quad = l >> 4;
  const int wr = w >> 2;           // 0..1 : row half (128 rows)
  const int wc = w & 3;            // 0..3 : col strip (32 cols)
  const int m0 = blockIdx.y * 256;
  const int n0g = blockIdx.x * 128;

  const int cb = ((quad * 8) ^ ((lr & 7) * 8));  // swizzled k-col base (elems)

  floatx4 acc[8][2];
#pragma unroll
  for (int mi = 0; mi < 8; ++mi)
#pragma unroll
    for (int nj = 0; nj < 2; ++nj) acc[mi][nj] = (floatx4){0.f, 0.f, 0.f, 0.f};

  const int NT = DIM / 64;  // 32 K-tiles

  // prologue: stage tiles 0 and 1 (6 gl_lds per wave each)
  stage_swz<256>(A, smem, m0, 0, w, l);
  stage_swz<128>(Bw, smem + 256 * 64, n0g, 0, w, l);
  stage_swz<256>(A, smem + BUFE, m0, 64, w, l);
  stage_swz<128>(Bw, smem + BUFE + 256 * 64, n0g, 64, w, l);
  VMCNT6;  // 12 outstanding -> oldest 6 (tile 0) landed
  S_BAR;

  for (int kt = 0; kt < NT; ++kt) {
    const bf16* la = smem + (kt % 3) * BUFE;
    const bf16* lb = la + 256 * 64;
    bf16* stg = smem + ((kt + 2) % 3) * BUFE;
    const bool do_stage = (kt + 2 < NT);

    // ---- phase A: B-frags + A-frags mi 0..3 ----
    short8 bfr[2][2];
#pragma unroll
    for (int nj = 0; nj < 2; ++nj) {
      int rb = (wc * 32 + nj * 16 + lr) * 64;
      bfr[nj][0] = *reinterpret_cast<const short8*>(lb + rb + cb);
      bfr[nj][1] = *reinterpret_cast<const short8*>(lb + rb + (cb ^ 32));
    }
    short8 af[4][2];
#pragma unroll
    for (int i = 0; i < 4; ++i) {
      int ra = (wr * 128 + i * 16 + lr) * 64;
      af[i][0] = *reinterpret_cast<const short8*>(la + ra + cb);
      af[i][1] = *reinterpret_cast<const short8*>(la + ra + (cb ^ 32));
    }
    if (do_stage) stage_swz<256>(A, stg, m0, (kt + 2) * 64, w, l);  // 4 gl_lds
    LGKM0;
    __builtin_amdgcn_s_setprio(1);
#pragma unroll
    for (int i = 0; i < 4; ++i)
#pragma unroll
      for (int nj = 0; nj < 2; ++nj) {
        acc[i][nj] = __builtin_amdgcn_mfma_f32_16x16x32_bf16(
            af[i][0], bfr[nj][0], acc[i][nj], 0, 0, 0);
        acc[i][nj] = __builtin_amdgcn_mfma_f32_16x16x32_bf16(
            af[i][1], bfr[nj][1], acc[i][nj], 0, 0, 0);
      }
    __builtin_amdgcn_s_setprio(0);

    // ---- phase B: A-frags mi 4..7 ----
#pragma unroll
    for (int i = 0; i < 4; ++i) {
      int ra = (wr * 128 + (i + 4) * 16 + lr) * 64;
      af[i][0] = *reinterpret_cast<const short8*>(la + ra + cb);
      af[i][1] = *reinterpret_cast<const short8*>(la + ra + (cb ^ 32));
    }
    if (do_stage) stage_swz<128>(Bw, stg + 256 * 64, n0g, (kt + 2) * 64, w, l);  // 2 gl_lds
    LGKM0;
    __builtin_amdgcn_s_setprio(1);
#pragma unroll
    for (int i = 0; i < 4; ++i)
#pragma unroll
      for (int nj = 0; nj < 2; ++nj) {
        acc[i + 4][nj] = __builtin_amdgcn_mfma_f32_16x16x32_bf16(
            af[i][0], bfr[nj][0], acc[i + 4][nj], 0, 0, 0);
        acc[i + 4][nj] = __builtin_amdgcn_mfma_f32_16x16x32_bf16(
            af[i][1], bfr[nj][1], acc[i + 4][nj], 0, 0, 0);
      }
    __builtin_amdgcn_s_setprio(0);

    // ---- tile end: publish buf[kt+1] ----
    if (do_stage) { VMCNT6; } else { VMCNT0; }
    S_BAR;
  }

  // ================= epilogue =================
  if constexpr (MODE == 1) {
#pragma unroll
    for (int mi = 0; mi < 8; ++mi)
#pragma unroll
      for (int nj = 0; nj < 2; ++nj) {
        int rg = m0 + wr * 128 + mi * 16 + quad * 4;
        int lcol = n0g + wc * 32 + nj * 16 + lr;
#pragma unroll
        for (int rr2 = 0; rr2 < 4; ++rr2)
          __builtin_nontemporal_store(acc[mi][nj][rr2],
                                      &Cout[(size_t)(rg + rr2) * DIM + lcol]);
      }
  } else {
    const int region = n0g >> 11;          // 0=Q, 1=K, 2=V
    const int h = (n0g & 2047) >> 7;       // 128-col tile == one head
    const int bb2 = m0 >> 11;
    const int sbase = m0 & (SEQ - 1);
    if (region < 2) {
      // ---- RoPE on f32 acc -> packed bf16 pairs -> LDS [256][132] ----
      short* T = reinterpret_cast<short*>(smem);
#pragma unroll
      for (int mi = 0; mi < 8; ++mi)
#pragma unroll
        for (int nj = 0; nj < 2; ++nj) {
          const int rl = wr * 128 + mi * 16 + quad * 4;   // local row
          const int d = wc * 32 + nj * 16 + lr;
          const int p = d >> 1;
#pragma unroll
          for (int rr2 = 0; rr2 < 4; ++rr2) {
            int row = m0 + rl + rr2;
            int s = row & (SEQ - 1);
            float v = acc[mi][nj][rr2];
            float prt = __shfl_xor(v, 1);
            float c = cosT[s * 64 + p], sn = sinT[s * 64 + p];
            float o = (lr & 1) ? (prt * sn + v * c) : (v * c - prt * sn);
            if (region == 1)
              __builtin_nontemporal_store(o, &Kout[(size_t)row * DIM + h * DKH + d]);
            BfBits bc; bc.h = __float2bfloat16(o);
            unsigned up = (unsigned short)bc.s;
            unsigned pp = __shfl_xor(up, 1);
            if (!(lr & 1)) {
              unsigned u32 = up | (pp << 16);
              *reinterpret_cast<unsigned*>(&T[(rl + rr2) * 132 + d]) = u32;
            }
          }
        }
      __syncthreads();
      // vectorized coalesced stores: 16 lanes x 16B = 256B contiguous
      bf16* dst = (region == 0) ? Qb : Kb;
#pragma unroll
      for (int u = 0; u < 8; ++u) {
        int row = u * 32 + (t >> 4);
        int d0 = (t & 15) * 8;
        short8 val = *reinterpret_cast<const short8*>(&T[row * 132 + d0]);
        size_t idx = ((size_t)(bb2 * NH + h) * SEQ + (sbase + row)) * DKH + d0;
        __builtin_nontemporal_store(val, reinterpret_cast<short8*>((short*)dst + idx));
      }
    } else {
      // ---- V: fp32 out + LDS transpose -> Vt (B,H,dk,S) bf16 ----
      short* T = reinterpret_cast<short*>(smem);   // [128][268] pad, 67 KB
#pragma unroll
      for (int mi = 0; mi < 8; ++mi)
#pragma unroll
        for (int nj = 0; nj < 2; ++nj) {
          const int d = wc * 32 + nj * 16 + lr;
          const int rl = wr * 128 + mi * 16 + quad * 4;  // local row 0..255
          const int rbase = m0 + rl;
#pragma unroll
          for (int rr2 = 0; rr2 < 4; ++rr2)
            __builtin_nontemporal_store(acc[mi][nj][rr2],
                &Vout[(size_t)(rbase + rr2) * DIM + h * DKH + d]);
          BfBits b0, b1, b2, b3;
          b0.h = __float2bfloat16(acc[mi][nj][0]);
          b1.h = __float2bfloat16(acc[mi][nj][1]);
          b2.h = __float2bfloat16(acc[mi][nj][2]);
          b3.h = __float2bfloat16(acc[mi][nj][3]);
          unsigned u0 = (unsigned short)b0.s | ((unsigned)(unsigned short)b1.s << 16);
          unsigned u1 = (unsigned short)b2.s | ((unsigned)(unsigned short)b3.s << 16);
          *reinterpret_cast<unsigned*>(&T[d * 268 + rl]) = u0;
          *reinterpret_cast<unsigned*>(&T[d * 268 + rl + 2]) = u1;
        }
      __syncthreads();
      // coalesced Vt stores: 16 lanes cover one d-row's 512B contiguously
      const int d2b = t >> 4;          // 0..31
      const int offb = (t & 15) * 16;  // shorts (32B per lane)
#pragma unroll
      for (int u = 0; u < 4; ++u) {
        int d2 = d2b + u * 32;
        short* vtp = (short*)Vt + ((size_t)(bb2 * NH + h) * DKH + d2) * SEQ + sbase + offb;
        intx4 v0 = *reinterpret_cast<const intx4*>(&T[d2 * 268 + offb]);
        intx4 v1 = *reinterpret_cast<const intx4*>(&T[d2 * 268 + offb + 8]);
        __builtin_nontemporal_store(v0, reinterpret_cast<intx4*>(vtp));
        __builtin_nontemporal_store(v1, reinterpret_cast<intx4*>(vtp + 8));
      }
    }
  }
}

// ---------------- MFMA flash attention (unchanged from R7) ---------------------
__global__ __launch_bounds__(256) void attn_mfma(const bf16* __restrict__ Qb,
                                                 const bf16* __restrict__ Kb,
                                                 const bf16* __restrict__ Vt,
                                                 bf16* __restrict__ ctx) {
  const int bx = blockIdx.x;  // 0..NQT/2-1
  const int h = blockIdx.y;
  const int b = blockIdx.z;
  const int t = threadIdx.x;
  const int w = t >> 6, lane = t & 63;
  const int lr = lane & 15, quad = lane >> 4;
  const int kswz = 8 * (lr & 7);   // read-side XOR (frag rows have row&7 == lr&7)

  __shared__ short Ks[2][64 * 128];   // swizzled content, linear layout, 16 KB
  __shared__ short Vs[2][128 * 64];   // swizzled content, linear layout, 16 KB
  __shared__ short Ps[4 * 16 * 72];   // per-wave P strips

  const float scale2 = 0.08838834764831845f * 1.44269504f;  // 1/sqrt(128)*log2e
  const float THR = 11.5413f;      // 8 * log2(e): defer-rescale threshold
  const size_t headQK = (size_t)(b * NH + h) * SEQ * DKH;
  const short* kbase0 = (const short*)Kb + headQK;
  const short* vbase0 = (const short*)Vt + (size_t)(b * NH + h) * DKH * SEQ;

  const int krow_l = w * 4 + (lane >> 4);          // + 16u
  const int kcol_l = ((lane & 15) * 8) ^ (8 * (krow_l & 7));
  const int vrow_l = w * 8 + (lane >> 3);          // + 32u
  const int vcol_l = ((lane & 7) * 8) ^ (8 * (vrow_l & 7));

  auto STAGE = [&](int kt, int buf) {
#pragma unroll
    for (int u = 0; u < 4; ++u) {
      gl_lds16((const bf16*)(kbase0 + (size_t)(kt * 64 + krow_l + 16 * u) * DKH + kcol_l),
               (bf16*)(&Ks[buf][(w * 64 + 256 * u) * 8]));
      gl_lds16((const bf16*)(vbase0 + (size_t)(vrow_l + 32 * u) * SEQ + kt * 64 + vcol_l),
               (bf16*)(&Vs[buf][(w * 64 + 256 * u) * 8]));
    }
  };

  for (int pass = 0; pass < 2; ++pass) {
    const int qt = pass ? bx : (NQT - 1 - bx);

    short8 qa[4];
    {
      const short* qbase = (const short*)Qb + headQK + (size_t)(qt * 64 + w * 16 + lr) * DKH;
#pragma unroll
      for (int kk = 0; kk < 4; ++kk)
        qa[kk] = *reinterpret_cast<const short8*>(qbase + kk * 32 + quad * 8);
    }

    floatx4 o[8];
#pragma unroll
    for (int n = 0; n < 8; ++n) o[n] = (floatx4){0.f, 0.f, 0.f, 0.f};
    float m[4] = {-1e30f, -1e30f, -1e30f, -1e30f};
    float l[4] = {0.f, 0.f, 0.f, 0.f};

    STAGE(0, 0);
    __syncthreads();   // drains vmcnt(0): tile 0 resident

    for (int kt = 0; kt <= qt; ++kt) {
      const int cur = kt & 1;
      if (kt < qt) STAGE(kt + 1, cur ^ 1);   // lands under this iter's compute
      const short* ksb = Ks[cur];
      const short* vsb = Vs[cur];

      floatx4 sj[4];
#pragma unroll
      for (int j = 0; j < 4; ++j) sj[j] = (floatx4){0.f, 0.f, 0.f, 0.f};
#pragma unroll
      for (int j = 0; j < 4; ++j)
#pragma unroll
        for (int kk = 0; kk < 4; ++kk) {
          short8 kb = *reinterpret_cast<const short8*>(
              ksb + (j * 16 + lr) * 128 + ((kk * 32 + quad * 8) ^ kswz));
          sj[j] = __builtin_amdgcn_mfma_f32_16x16x32_bf16(qa[kk], kb, sj[j], 0, 0, 0);
        }

      float sc[4][4];
#pragma unroll
      for (int j = 0; j < 4; ++j)
#pragma unroll
        for (int r = 0; r < 4; ++r) sc[j][r] = sj[j][r] * scale2;
      if (kt == qt) {
#pragma unroll
        for (int j = 0; j < 4; ++j) {
          int col = kt * 64 + j * 16 + lr;
#pragma unroll
          for (int r = 0; r < 4; ++r) {
            int rowg = qt * 64 + w * 16 + quad * 4 + r;
            if (col > rowg) sc[j][r] = -1e9f;
          }
        }
      }

#pragma unroll
      for (int r = 0; r < 4; ++r) {
        float mx = fmaxf(fmaxf(sc[0][r], sc[1][r]), fmaxf(sc[2][r], sc[3][r]));
        mx = fmaxf(mx, __shfl_xor(mx, 1, 16));
        mx = fmaxf(mx, __shfl_xor(mx, 2, 16));
        mx = fmaxf(mx, __shfl_xor(mx, 4, 16));
        mx = fmaxf(mx, __shfl_xor(mx, 8, 16));
        if (!__all(mx - m[r] <= THR)) {
          float mnew = fmaxf(m[r], mx);
          float alpha = __builtin_amdgcn_exp2f(m[r] - mnew);
          l[r] *= alpha;
#pragma unroll
          for (int n = 0; n < 8; ++n) o[n][r] *= alpha;
          m[r] = mnew;
        }
        float rs = 0.f;
#pragma unroll
        for (int j = 0; j < 4; ++j) {
          float p = __builtin_amdgcn_exp2f(sc[j][r] - m[r]);
          rs += p;
          BfBits u; u.h = __float2bfloat16(p);
          Ps[(w * 16 + quad * 4 + r) * 72 + j * 16 + lr] = u.s;
        }
        rs += __shfl_xor(rs, 1, 16);
        rs += __shfl_xor(rs, 2, 16);
        rs += __shfl_xor(rs, 4, 16);
        rs += __shfl_xor(rs, 8, 16);
        l[r] += rs;
      }

      short8 pa0 = *reinterpret_cast<const short8*>(Ps + (w * 16 + lr) * 72 + quad * 8);
      short8 pa1 = *reinterpret_cast<const short8*>(Ps + (w * 16 + lr) * 72 + 32 + quad * 8);
#pragma unroll
      for (int n = 0; n < 8; ++n) {
        short8 vb0 = *reinterpret_cast<const short8*>(
            vsb + (n * 16 + lr) * 64 + ((quad * 8) ^ kswz));
        short8 vb1 = *reinterpret_cast<const short8*>(
            vsb + (n * 16 + lr) * 64 + ((32 + quad * 8) ^ kswz));
        o[n] = __builtin_amdgcn_mfma_f32_16x16x32_bf16(pa0, vb0, o[n], 0, 0, 0);
        o[n] = __builtin_amdgcn_mfma_f32_16x16x32_bf16(pa1, vb1, o[n], 0, 0, 0);
      }
      __syncthreads();  // drains vmcnt (kt+1 staged) + lgkm; publishes buf^1
    }

    float inv[4];
#pragma unroll
    for (int r = 0; r < 4; ++r) inv[r] = 1.0f / l[r];
#pragma unroll
    for (int r = 0; r < 4; ++r) {
      size_t mrow = (size_t)b * SEQ + qt * 64 + w * 16 + quad * 4 + r;
      bf16* dst = ctx + mrow * DIM + h * DKH;
#pragma unroll
      for (int n = 0; n < 8; ++n)
        dst[n * 16 + lr] = __float2bfloat16(o[n][r] * inv[r]);
    }
  }
}

// ---------------- launch ----------------
extern "C" void kernel_launch(void* const* d_in, const int* in_sizes, int n_in,
                              void* d_out, int out_size, void* d_ws, size_t ws_size,
                              hipStream_t stream) {
  const float* x = (const float*)d_in[0];
  const float* fcos = (const float*)d_in[1];
  const float* fsin = (const float*)d_in[2];
  // d_in[3] = mask (causal applied analytically)
  const float* Wq = (const float*)d_in[4];
  const float* Wk = (const float*)d_in[5];
  const float* Wv = (const float*)d_in[6];
  const float* Wo = (const float*)d_in[7];

  float* out = (float*)d_out;                  // M x D
  float* Kout = out + (size_t)MROWS * DIM;     // K cache (fp32, post-RoPE)
  float* Vout = Kout + (size_t)MROWS * DIM;    // V cache (fp32)

  const size_t MD = (size_t)MROWS * DIM;       // 8.39M
  const size_t DD = (size_t)DIM * DIM;         // 4.19M
  bf16* xb   = (bf16*)d_ws;          // MD
  bf16* Wqb  = xb + MD;              // DD x4 (contiguous: fused QKV B-matrix)
  bf16* Wkb  = Wqb + DD;
  bf16* Wvb  = Wkb + DD;
  bf16* Wob  = Wvb + DD;
  bf16* Qb   = Wob + DD;             // MD  (post-RoPE, (B,H,S,dk))
  bf16* Kb   = Qb + MD;              // MD  (post-RoPE, (B,H,S,dk))
  bf16* Vt   = Kb + MD;              // MD  ((B,H,dk,S))
  bf16* ctxb = Vt + MD;              // MD

  const int nXD4 = MROWS * DIM / 4;  // 2^21
  const int nWD4 = DIM * DIM / 4;    // 2^20
  const int nTot = nXD4 + 4 * nWD4;  // 6,291,456
  cast5_kernel<<<nTot / 256, 256, 0, stream>>>(x, Wq, Wk, Wv, Wo, xb, nXD4, nWD4, nTot);

  // fused QKV projection + RoPE + V-transpose epilogue: grid 48x16
  dim3 gq(3 * DIM / 128, MROWS / 256);
  gemm256<0><<<gq, 512, 0, stream>>>(xb, Wqb, Qb, Kb, Kout, Vout, Vt, fcos, fsin,
                                     (float*)nullptr);

  dim3 ga(NQT / 2, NH, BATCH);  // (16, 16, 2) — paired q-tiles, uniform 33 iters
  attn_mfma<<<ga, 256, 0, stream>>>(Qb, Kb, Vt, ctxb);

  // output projection: grid 16x16 = 256 = 1/CU
  dim3 go(DIM / 128, MROWS / 256);
  gemm256<1><<<go, 512, 0, stream>>>(ctxb, Wob, (bf16*)nullptr, (bf16*)nullptr,
                                     (float*)nullptr, (float*)nullptr, (bf16*)nullptr,
                                     (const float*)nullptr, (const float*)nullptr, out);
}

// Round 11
// 443.832 us; speedup vs baseline: 1.0909x; 1.0909x over previous
//
#include <hip/hip_runtime.h>
#include <hip/hip_bf16.h>

// Problem constants (B=2, S=2048, D=2048, H=16, dk=128)
#define SEQ   2048
#define DIM   2048
#define NH    16
#define DKH   128
#define BATCH 2
#define MROWS (BATCH * SEQ)   // 4096
#define NQT   (SEQ / 64)      // 32 q-tiles per (b,h)

using bf16 = __hip_bfloat16;
typedef __attribute__((ext_vector_type(8))) short short8;
typedef __attribute__((ext_vector_type(4))) short short4v;
typedef __attribute__((ext_vector_type(4))) float floatx4;

union BfBits { bf16 h; short s; };

// async global->LDS, 16 bytes per lane (wave-uniform LDS base + lane*16;
// global source address is per-lane)
__device__ __forceinline__ void gl_lds16(const bf16* g, bf16* l) {
  __builtin_amdgcn_global_load_lds(
      (__attribute__((address_space(1))) void*)(g),
      (__attribute__((address_space(3))) void*)(l), 16, 0, 0);
}

#define S_BAR  __builtin_amdgcn_s_barrier()
#define VMCNT6 do { asm volatile("s_waitcnt vmcnt(6)" ::: "memory"); __builtin_amdgcn_sched_barrier(0); } while (0)
#define VMCNT0 do { asm volatile("s_waitcnt vmcnt(0)" ::: "memory"); __builtin_amdgcn_sched_barrier(0); } while (0)
#define LGKM0  do { asm volatile("s_waitcnt lgkmcnt(0)" ::: "memory"); __builtin_amdgcn_sched_barrier(0); } while (0)

// ---------------- merged cast fp32 -> bf16 for x + 4 weights ----------------
__global__ __launch_bounds__(256) void cast5_kernel(const float* __restrict__ x,
                                                    const float* __restrict__ wq,
                                                    const float* __restrict__ wk,
                                                    const float* __restrict__ wv,
                                                    const float* __restrict__ wo,
                                                    bf16* __restrict__ dst,
                                                    int nX4, int nW4, int nTot) {
  int i = blockIdx.x * 256 + threadIdx.x;
  if (i >= nTot) return;
  const float* src;
  int off;
  int j = i - nX4;
  if (j < 0) { src = x; off = i; }
  else {
    int wsel = j >> 20;          // nW4 = 2^20
    off = j & (nW4 - 1);
    src = (wsel == 0) ? wq : (wsel == 1) ? wk : (wsel == 2) ? wv : wo;
  }
  float4 v = reinterpret_cast<const float4*>(src)[off];
  __hip_bfloat162 h01, h23;
  h01.x = __float2bfloat16(v.x); h01.y = __float2bfloat16(v.y);
  h23.x = __float2bfloat16(v.z); h23.y = __float2bfloat16(v.w);
  reinterpret_cast<__hip_bfloat162*>(dst)[i * 2 + 0] = h01;
  reinterpret_cast<__hip_bfloat162*>(dst)[i * 2 + 1] = h23;
}

// ============ pipelined 256x128 GEMM, BK=64, 3-buffer, phase-interleaved =====
// K-loop identical to R5 (114.8 us, MfmaUtil 39.4%, conflicts 0).
// R11: XCD-aware block swizzle (T1): 1D grid, bijective chunked remap
// (nwg % 8 == 0). Each XCD gets nwg/8 consecutive LOGICAL tiles = 2 full
// M-rows -> the 1MB A-panel is L2-resident per XCD.
#define BUFE (256 * 64 + 128 * 64)   // 24576 elems per buffer

template <int ROWS>
__device__ __forceinline__ void stage_swz(const bf16* __restrict__ G, bf16* lds,
                                          int row0, int k0, int w, int l) {
  const int rr = w * 8 + (l >> 3);                 // row within 64-row issue
  const int cc = ((l & 7) * 8) ^ ((l >> 3) * 8);   // pre-swizzled col (elems)
#pragma unroll
  for (int u = 0; u < ROWS / 64; ++u)
    gl_lds16(G + (size_t)(row0 + u * 64 + rr) * DIM + k0 + cc,
             lds + (u * 64 + w * 8) * 64);
}

// MODE 0: QKV routing (N=6144, grid 768). MODE 1: fp32 C via Kout (N=2048, grid 256).
template <int MODE>
__global__ __launch_bounds__(512, 2) void gemm256(const bf16* __restrict__ A,
                                                  const bf16* __restrict__ Bw,
                                                  bf16* __restrict__ Qraw,
                                                  float* __restrict__ Kout,
                                                  float* __restrict__ Vout) {
  __shared__ bf16 smem[3 * BUFE];  // [buf] { A 256x64 | B 128x64 }

  // XCD swizzle: orig -> logical, chunked per XCD (bijective, nwg%8==0)
  constexpr int NWG = (MODE == 0) ? 768 : 256;
  constexpr int NX  = (MODE == 0) ? 48 : 16;
  const int orig = blockIdx.x;
  const int logical = (orig & 7) * (NWG / 8) + (orig >> 3);
  const int m0 = (logical / NX) * 256;
  const int n0g = (logical % NX) * 128;

  const int t = threadIdx.x;
  const int w = t >> 6, l = t & 63;
  const int lr = l & 15, quad = l >> 4;
  const int wr = w >> 2;           // 0..1 : row half (128 rows)
  const int wc = w & 3;            // 0..3 : col strip (32 cols)

  const int cb = ((quad * 8) ^ ((lr & 7) * 8));  // swizzled k-col base (elems)

  floatx4 acc[8][2];
#pragma unroll
  for (int mi = 0; mi < 8; ++mi)
#pragma unroll
    for (int nj = 0; nj < 2; ++nj) acc[mi][nj] = (floatx4){0.f, 0.f, 0.f, 0.f};

  const int NT = DIM / 64;  // 32 K-tiles

  // prologue: stage tiles 0 and 1 (6 gl_lds per wave each)
  stage_swz<256>(A, smem, m0, 0, w, l);
  stage_swz<128>(Bw, smem + 256 * 64, n0g, 0, w, l);
  stage_swz<256>(A, smem + BUFE, m0, 64, w, l);
  stage_swz<128>(Bw, smem + BUFE + 256 * 64, n0g, 64, w, l);
  VMCNT6;  // 12 outstanding -> oldest 6 (tile 0) landed
  S_BAR;

  for (int kt = 0; kt < NT; ++kt) {
    const bf16* la = smem + (kt % 3) * BUFE;
    const bf16* lb = la + 256 * 64;
    bf16* stg = smem + ((kt + 2) % 3) * BUFE;
    const bool do_stage = (kt + 2 < NT);

    // ---- phase A: B-frags + A-frags mi 0..3 ----
    short8 bfr[2][2];
#pragma unroll
    for (int nj = 0; nj < 2; ++nj) {
      int rb = (wc * 32 + nj * 16 + lr) * 64;
      bfr[nj][0] = *reinterpret_cast<const short8*>(lb + rb + cb);
      bfr[nj][1] = *reinterpret_cast<const short8*>(lb + rb + (cb ^ 32));
    }
    short8 af[4][2];
#pragma unroll
    for (int i = 0; i < 4; ++i) {
      int ra = (wr * 128 + i * 16 + lr) * 64;
      af[i][0] = *reinterpret_cast<const short8*>(la + ra + cb);
      af[i][1] = *reinterpret_cast<const short8*>(la + ra + (cb ^ 32));
    }
    if (do_stage) stage_swz<256>(A, stg, m0, (kt + 2) * 64, w, l);  // 4 gl_lds
    LGKM0;
    __builtin_amdgcn_s_setprio(1);
#pragma unroll
    for (int i = 0; i < 4; ++i)
#pragma unroll
      for (int nj = 0; nj < 2; ++nj) {
        acc[i][nj] = __builtin_amdgcn_mfma_f32_16x16x32_bf16(
            af[i][0], bfr[nj][0], acc[i][nj], 0, 0, 0);
        acc[i][nj] = __builtin_amdgcn_mfma_f32_16x16x32_bf16(
            af[i][1], bfr[nj][1], acc[i][nj], 0, 0, 0);
      }
    __builtin_amdgcn_s_setprio(0);

    // ---- phase B: A-frags mi 4..7 ----
#pragma unroll
    for (int i = 0; i < 4; ++i) {
      int ra = (wr * 128 + (i + 4) * 16 + lr) * 64;
      af[i][0] = *reinterpret_cast<const short8*>(la + ra + cb);
      af[i][1] = *reinterpret_cast<const short8*>(la + ra + (cb ^ 32));
    }
    if (do_stage) stage_swz<128>(Bw, stg + 256 * 64, n0g, (kt + 2) * 64, w, l);  // 2 gl_lds
    LGKM0;
    __builtin_amdgcn_s_setprio(1);
#pragma unroll
    for (int i = 0; i < 4; ++i)
#pragma unroll
      for (int nj = 0; nj < 2; ++nj) {
        acc[i + 4][nj] = __builtin_amdgcn_mfma_f32_16x16x32_bf16(
            af[i][0], bfr[nj][0], acc[i + 4][nj], 0, 0, 0);
        acc[i + 4][nj] = __builtin_amdgcn_mfma_f32_16x16x32_bf16(
            af[i][1], bfr[nj][1], acc[i + 4][nj], 0, 0, 0);
      }
    __builtin_amdgcn_s_setprio(0);

    // ---- tile end: publish buf[kt+1] ----
    if (do_stage) { VMCNT6; } else { VMCNT0; }
    S_BAR;
  }

  // epilogue
#pragma unroll
  for (int mi = 0; mi < 8; ++mi)
#pragma unroll
    for (int nj = 0; nj < 2; ++nj) {
      int rg = m0 + wr * 128 + mi * 16 + quad * 4;
      if constexpr (MODE == 0) {
        const int region = n0g >> 11;
        int lcol = (n0g & 2047) + wc * 32 + nj * 16 + lr;
#pragma unroll
        for (int rr2 = 0; rr2 < 4; ++rr2) {
          size_t idx = (size_t)(rg + rr2) * DIM + lcol;
          if (region == 0)      Qraw[idx] = __float2bfloat16(acc[mi][nj][rr2]);
          else if (region == 1) Kout[idx] = acc[mi][nj][rr2];
          else                  Vout[idx] = acc[mi][nj][rr2];
        }
      } else {
        int lcol = n0g + wc * 32 + nj * 16 + lr;
#pragma unroll
        for (int rr2 = 0; rr2 < 4; ++rr2)
          Kout[(size_t)(rg + rr2) * DIM + lcol] = acc[mi][nj][rr2];
      }
    }
}

// ---------------- fused postproc: rope_q | rope_k | V transpose ----------------
#define NRB ((MROWS * DIM / 2) / 256)   // 16384 blocks per rope part

__global__ __launch_bounds__(256) void postproc(const bf16* __restrict__ Qraw,
                                                float* __restrict__ Kf,
                                                const float* __restrict__ cosT,
                                                const float* __restrict__ sinT,
                                                bf16* __restrict__ Qb,
                                                bf16* __restrict__ Kb,
                                                const float* __restrict__ V,
                                                bf16* __restrict__ Vt) {
  int bid = blockIdx.x;
  if (bid < NRB) {
    // ---- rope_q ----
    int g = bid * 256 + threadIdx.x;
    int p = g & 63;
    int r = g >> 6;
    int h = r & 15;
    int s = (r >> 4) & (SEQ - 1);
    int b = r >> 15;
    __hip_bfloat162 v = reinterpret_cast<const __hip_bfloat162*>(Qraw)[g];
    float x0 = __bfloat162float(v.x), x1 = __bfloat162float(v.y);
    float c = cosT[s * 64 + p], sn = sinT[s * 64 + p];
    __hip_bfloat162 o;
    o.x = __float2bfloat16(x0 * c - x1 * sn);
    o.y = __float2bfloat16(x0 * sn + x1 * c);
    reinterpret_cast<__hip_bfloat162*>(Qb)[((size_t)(b * NH + h) * SEQ + s) * 64 + p] = o;
    return;
  }
  bid -= NRB;
  if (bid < NRB) {
    // ---- rope_k ----
    int g = bid * 256 + threadIdx.x;
    int p = g & 63;
    int r = g >> 6;
    int h = r & 15;
    int s = (r >> 4) & (SEQ - 1);
    int b = r >> 15;
    float2 v = reinterpret_cast<const float2*>(Kf)[g];
    float c = cosT[s * 64 + p], sn = sinT[s * 64 + p];
    float o0 = v.x * c - v.y * sn;
    float o1 = v.x * sn + v.y * c;
    reinterpret_cast<float2*>(Kf)[g] = make_float2(o0, o1);
    __hip_bfloat162 ob;
    ob.x = __float2bfloat16(o0);
    ob.y = __float2bfloat16(o1);
    reinterpret_cast<__hip_bfloat162*>(Kb)[((size_t)(b * NH + h) * SEQ + s) * 64 + p] = ob;
    return;
  }
  bid -= NRB;
  {
    // ---- vt : bid in [0, 8192) = (x:64, y:4, z:32) ----
    __shared__ float tile[32][33];
    const int s0 = (bid & 63) * 32;
    const int d0 = ((bid >> 6) & 3) * 32;
    const int bh = bid >> 8;
    const int b = bh >> 4, h = bh & 15;
    const int t = threadIdx.x;
    const int row = t >> 3, c4 = (t & 7) * 4;

    float4 v = *reinterpret_cast<const float4*>(
        V + (size_t)(b * SEQ + s0 + row) * DIM + h * DKH + d0 + c4);
    tile[row][c4 + 0] = v.x; tile[row][c4 + 1] = v.y;
    tile[row][c4 + 2] = v.z; tile[row][c4 + 3] = v.w;
    __syncthreads();

    short4v ov;
#pragma unroll
    for (int i = 0; i < 4; ++i) {
      BfBits u; u.h = __float2bfloat16(tile[c4 + i][row]);
      ov[i] = u.s;
    }
    *reinterpret_cast<short4v*>(Vt + ((size_t)(b * NH + h) * DKH + d0 + row) * SEQ + s0 + c4) = ov;
  }
}

// ---------------- MFMA flash attention ----------------------------------------
// R7 structure (K/V via global_load_lds, pre-swizzled source, dbuf, one
// barrier/iter) + R11 XCD swizzle: 1D grid of 512, chunked remap so each XCD
// owns 64 consecutive logical blocks = 4 complete heads = 4MB KV = its L2.
__global__ __launch_bounds__(256) void attn_mfma(const bf16* __restrict__ Qb,
                                                 const bf16* __restrict__ Kb,
                                                 const bf16* __restrict__ Vt,
                                                 bf16* __restrict__ ctx) {
  const int orig = blockIdx.x;                     // 0..511
  const int logical = (orig & 7) * 64 + (orig >> 3);  // bijective (512%8==0)
  const int bx = logical & 15;          // q-tile pair
  const int h = (logical >> 4) & 15;    // head
  const int b = logical >> 8;           // batch
  const int t = threadIdx.x;
  const int w = t >> 6, lane = t & 63;
  const int lr = lane & 15, quad = lane >> 4;
  const int kswz = 8 * (lr & 7);   // read-side XOR (frag rows have row&7 == lr&7)

  __shared__ short Ks[2][64 * 128];   // swizzled content, linear layout, 16 KB
  __shared__ short Vs[2][128 * 64];   // swizzled content, linear layout, 16 KB
  __shared__ short Ps[4 * 16 * 72];   // per-wave P strips

  const float scale2 = 0.08838834764831845f * 1.44269504f;  // 1/sqrt(128)*log2e
  const float THR = 11.5413f;      // 8 * log2(e): defer-rescale threshold
  const size_t headQK = (size_t)(b * NH + h) * SEQ * DKH;
  const short* kbase0 = (const short*)Kb + headQK;
  const short* vbase0 = (const short*)Vt + (size_t)(b * NH + h) * DKH * SEQ;

  const int krow_l = w * 4 + (lane >> 4);          // + 16u
  const int kcol_l = ((lane & 15) * 8) ^ (8 * (krow_l & 7));
  const int vrow_l = w * 8 + (lane >> 3);          // + 32u
  const int vcol_l = ((lane & 7) * 8) ^ (8 * (vrow_l & 7));

  auto STAGE = [&](int kt, int buf) {
#pragma unroll
    for (int u = 0; u < 4; ++u) {
      gl_lds16((const bf16*)(kbase0 + (size_t)(kt * 64 + krow_l + 16 * u) * DKH + kcol_l),
               (bf16*)(&Ks[buf][(w * 64 + 256 * u) * 8]));
      gl_lds16((const bf16*)(vbase0 + (size_t)(vrow_l + 32 * u) * SEQ + kt * 64 + vcol_l),
               (bf16*)(&Vs[buf][(w * 64 + 256 * u) * 8]));
    }
  };

  for (int pass = 0; pass < 2; ++pass) {
    const int qt = pass ? bx : (NQT - 1 - bx);

    short8 qa[4];
    {
      const short* qbase = (const short*)Qb + headQK + (size_t)(qt * 64 + w * 16 + lr) * DKH;
#pragma unroll
      for (int kk = 0; kk < 4; ++kk)
        qa[kk] = *reinterpret_cast<const short8*>(qbase + kk * 32 + quad * 8);
    }

    floatx4 o[8];
#pragma unroll
    for (int n = 0; n < 8; ++n) o[n] = (floatx4){0.f, 0.f, 0.f, 0.f};
    float m[4] = {-1e30f, -1e30f, -1e30f, -1e30f};
    float l[4] = {0.f, 0.f, 0.f, 0.f};

    STAGE(0, 0);
    __syncthreads();   // drains vmcnt(0): tile 0 resident

    for (int kt = 0; kt <= qt; ++kt) {
      const int cur = kt & 1;
      if (kt < qt) STAGE(kt + 1, cur ^ 1);   // lands under this iter's compute
      const short* ksb = Ks[cur];
      const short* vsb = Vs[cur];

      floatx4 sj[4];
#pragma unroll
      for (int j = 0; j < 4; ++j) sj[j] = (floatx4){0.f, 0.f, 0.f, 0.f};
#pragma unroll
      for (int j = 0; j < 4; ++j)
#pragma unroll
        for (int kk = 0; kk < 4; ++kk) {
          short8 kb = *reinterpret_cast<const short8*>(
              ksb + (j * 16 + lr) * 128 + ((kk * 32 + quad * 8) ^ kswz));
          sj[j] = __builtin_amdgcn_mfma_f32_16x16x32_bf16(qa[kk], kb, sj[j], 0, 0, 0);
        }

      float sc[4][4];
#pragma unroll
      for (int j = 0; j < 4; ++j)
#pragma unroll
        for (int r = 0; r < 4; ++r) sc[j][r] = sj[j][r] * scale2;
      if (kt == qt) {
#pragma unroll
        for (int j = 0; j < 4; ++j) {
          int col = kt * 64 + j * 16 + lr;
#pragma unroll
          for (int r = 0; r < 4; ++r) {
            int rowg = qt * 64 + w * 16 + quad * 4 + r;
            if (col > rowg) sc[j][r] = -1e9f;
          }
        }
      }

#pragma unroll
      for (int r = 0; r < 4; ++r) {
        float mx = fmaxf(fmaxf(sc[0][r], sc[1][r]), fmaxf(sc[2][r], sc[3][r]));
        mx = fmaxf(mx, __shfl_xor(mx, 1, 16));
        mx = fmaxf(mx, __shfl_xor(mx, 2, 16));
        mx = fmaxf(mx, __shfl_xor(mx, 4, 16));
        mx = fmaxf(mx, __shfl_xor(mx, 8, 16));
        if (!__all(mx - m[r] <= THR)) {
          float mnew = fmaxf(m[r], mx);
          float alpha = __builtin_amdgcn_exp2f(m[r] - mnew);
          l[r] *= alpha;
#pragma unroll
          for (int n = 0; n < 8; ++n) o[n][r] *= alpha;
          m[r] = mnew;
        }
        float rs = 0.f;
#pragma unroll
        for (int j = 0; j < 4; ++j) {
          float p = __builtin_amdgcn_exp2f(sc[j][r] - m[r]);
          rs += p;
          BfBits u; u.h = __float2bfloat16(p);
          Ps[(w * 16 + quad * 4 + r) * 72 + j * 16 + lr] = u.s;
        }
        rs += __shfl_xor(rs, 1, 16);
        rs += __shfl_xor(rs, 2, 16);
        rs += __shfl_xor(rs, 4, 16);
        rs += __shfl_xor(rs, 8, 16);
        l[r] += rs;
      }

      short8 pa0 = *reinterpret_cast<const short8*>(Ps + (w * 16 + lr) * 72 + quad * 8);
      short8 pa1 = *reinterpret_cast<const short8*>(Ps + (w * 16 + lr) * 72 + 32 + quad * 8);
#pragma unroll
      for (int n = 0; n < 8; ++n) {
        short8 vb0 = *reinterpret_cast<const short8*>(
            vsb + (n * 16 + lr) * 64 + ((quad * 8) ^ kswz));
        short8 vb1 = *reinterpret_cast<const short8*>(
            vsb + (n * 16 + lr) * 64 + ((32 + quad * 8) ^ kswz));
        o[n] = __builtin_amdgcn_mfma_f32_16x16x32_bf16(pa0, vb0, o[n], 0, 0, 0);
        o[n] = __builtin_amdgcn_mfma_f32_16x16x32_bf16(pa1, vb1, o[n], 0, 0, 0);
      }
      __syncthreads();  // drains vmcnt (kt+1 staged) + lgkm; publishes buf^1
    }

    float inv[4];
#pragma unroll
    for (int r = 0; r < 4; ++r) inv[r] = 1.0f / l[r];
#pragma unroll
    for (int r = 0; r < 4; ++r) {
      size_t mrow = (size_t)b * SEQ + qt * 64 + w * 16 + quad * 4 + r;
      bf16* dst = ctx + mrow * DIM + h * DKH;
#pragma unroll
      for (int n = 0; n < 8; ++n)
        dst[n * 16 + lr] = __float2bfloat16(o[n][r] * inv[r]);
    }
  }
}

// ---------------- launch ----------------
extern "C" void kernel_launch(void* const* d_in, const int* in_sizes, int n_in,
                              void* d_out, int out_size, void* d_ws, size_t ws_size,
                              hipStream_t stream) {
  const float* x = (const float*)d_in[0];
  const float* fcos = (const float*)d_in[1];
  const float* fsin = (const float*)d_in[2];
  // d_in[3] = mask (causal applied analytically)
  const float* Wq = (const float*)d_in[4];
  const float* Wk = (const float*)d_in[5];
  const float* Wv = (const float*)d_in[6];
  const float* Wo = (const float*)d_in[7];

  float* out = (float*)d_out;                  // M x D
  float* Kout = out + (size_t)MROWS * DIM;     // K cache (fp32, post-RoPE)
  float* Vout = Kout + (size_t)MROWS * DIM;    // V cache (fp32)

  const size_t MD = (size_t)MROWS * DIM;       // 8.39M
  const size_t DD = (size_t)DIM * DIM;         // 4.19M
  bf16* xb   = (bf16*)d_ws;          // MD
  bf16* Wqb  = xb + MD;              // DD x4 (contiguous: fused QKV B-matrix)
  bf16* Wkb  = Wqb + DD;
  bf16* Wvb  = Wkb + DD;
  bf16* Wob  = Wvb + DD;
  bf16* Qraw = Wob + DD;             // MD  (pre-RoPE Q, (B,S,D)); reused as ctxb
  bf16* Qb   = Qraw + MD;            // MD  (post-RoPE, (B,H,S,dk))
  bf16* Kb   = Qb + MD;              // MD  (post-RoPE, (B,H,S,dk))
  bf16* Vt   = Kb + MD;              // MD  ((B,H,dk,S))
  bf16* ctxb = Qraw;                 // alias: Qraw dead after postproc

  const int nXD4 = MROWS * DIM / 4;  // 2^21
  const int nWD4 = DIM * DIM / 4;    // 2^20
  const int nTot = nXD4 + 4 * nWD4;  // 6,291,456
  cast5_kernel<<<nTot / 256, 256, 0, stream>>>(x, Wq, Wk, Wv, Wo, xb, nXD4, nWD4, nTot);

  // fused QKV projection: 1D grid 768, XCD-swizzled
  gemm256<0><<<768, 512, 0, stream>>>(xb, Wqb, Qraw, Kout, Vout);

  // fused rope_q + rope_k + vt (one launch)
  postproc<<<2 * NRB + 8192, 256, 0, stream>>>(Qraw, Kout, fcos, fsin, Qb, Kb, Vout, Vt);

  // attention: 1D grid 512, XCD-swizzled (4 heads per XCD -> KV L2-resident)
  attn_mfma<<<512, 256, 0, stream>>>(Qb, Kb, Vt, ctxb);

  // output projection: 1D grid 256, XCD-swizzled
  gemm256<1><<<256, 512, 0, stream>>>(ctxb, Wob, (bf16*)nullptr, out, (float*)nullptr);
}